// Round 15
// baseline (1178.635 us; speedup 1.0000x reference)
//
#include <hip/hip_runtime.h>
#include <hip/hip_bf16.h>
#include <math.h>

constexpr int HW = 4000;
constexpr int HP = 4284;            // haloed pixels per image (42*102)
constexpr int HPAD = 4480;          // plane stride in pixels (incl. staging slack)
constexpr int NPIXH = 16 * HP;      // 68544

typedef short s16x8 __attribute__((ext_vector_type(8)));
typedef float f32x4 __attribute__((ext_vector_type(4)));
typedef unsigned short u16x4 __attribute__((ext_vector_type(4)));
typedef unsigned short u16;

__device__ __forceinline__ u16 f2bf(float f) {
    __hip_bfloat16 h = __float2bfloat16(f);
    u16 b; __builtin_memcpy(&b, &h, 2); return b;
}
__device__ __forceinline__ float bf2f(u16 b) {
    __hip_bfloat16 h; __builtin_memcpy(&h, &b, 2); return __bfloat162float(h);
}

__device__ __forceinline__ void gload_lds16(const void* g, void* l) {
    __builtin_amdgcn_global_load_lds(
        (const __attribute__((address_space(1))) void*)g,
        (__attribute__((address_space(3))) void*)l, 16, 0, 0);
}

// ---------------------------------------------------------------------------
// Weight repack: OIHW fp32 -> [rs][ch][Npad*4 chunks][8] bf16 hi (+ lo).
// chunk q: f=q>>6, g=(q>>4)&3, rA=q&15 -> n=f*16+rA, c=ch*32+g*8+j
// ---------------------------------------------------------------------------
__global__ __launch_bounds__(256) void repack_w(
    const float* __restrict__ W, u16* __restrict__ Wh, u16* __restrict__ Wl,
    int Cout, int Cin, int NRS, int nCh, int Npad, int do_lo)
{
    const int chunk = blockIdx.x * 256 + threadIdx.x;
    const int per = Npad * 4;
    const int total = NRS * nCh * per;
    if (chunk >= total) return;
    const int q = chunk % per;
    const int t2 = chunk / per;
    const int ch = t2 % nCh;
    const int rs = t2 / nCh;
    const int f = q >> 6, g = (q >> 4) & 3, rA = q & 15;
    const int n = f * 16 + rA;
    u16x4 hp[2], lp[2];
    #pragma unroll
    for (int j = 0; j < 8; ++j) {
        const int c = ch * 32 + g * 8 + j;
        const float v = (n < Cout && c < Cin) ? W[((size_t)n * Cin + c) * NRS + rs] : 0.f;
        const u16 hb = f2bf(v);
        hp[j >> 2][j & 3] = hb;
        lp[j >> 2][j & 3] = f2bf(v - bf2f(hb));
    }
    const size_t o = (size_t)chunk * 8;
    *(u16x4*)(Wh + o) = hp[0]; *(u16x4*)(Wh + o + 4) = hp[1];
    if (do_lo) { *(u16x4*)(Wl + o) = lp[0]; *(u16x4*)(Wl + o + 4) = lp[1]; }
}

// ---------------------------------------------------------------------------
// features NCHW fp32 -> planar-chunked haloed bf16 hi+lo (36 planes of 8 ch)
// channels: 0=x, 1=y, 2..257=f, 258..287=0
// ---------------------------------------------------------------------------
__global__ __launch_bounds__(256) void prep_x0(
    const float* __restrict__ feat, u16* __restrict__ Xh, u16* __restrict__ Xl)
{
    const int p = blockIdx.x * 256 + threadIdx.x;
    if (p >= NPIXH) return;
    const int b = p / HP; const int rem = p - b * HP;
    const int hh = rem / 102, wp = rem - hh * 102;
    const bool halo = (hh == 0) | (hh == 41) | (wp == 0) | (wp == 101);
    const int h = hh - 1, w = wp - 1;
    const int hw = h * 100 + w;
    const float xw = -1.f + 2.f * (float)w / 99.f;
    const float yh = -1.f + 2.f * (float)h / 39.f;
    for (int g = 0; g < 36; ++g) {
        u16x4 hp[2], lp[2];
        #pragma unroll
        for (int j = 0; j < 8; ++j) {
            const int c = g * 8 + j;
            float v = 0.f;
            if (!halo) {
                if (c == 0) v = xw;
                else if (c == 1) v = yh;
                else if (c < 258) v = feat[((size_t)(b * 256 + (c - 2))) * HW + hw];
            }
            const u16 hb = f2bf(v);
            hp[j >> 2][j & 3] = hb;
            lp[j >> 2][j & 3] = f2bf(v - bf2f(hb));
        }
        const size_t o = ((size_t)(b * 36 + g) * HPAD + rem) * 8;
        *(u16x4*)(Xh + o) = hp[0]; *(u16x4*)(Xh + o + 4) = hp[1];
        *(u16x4*)(Xl + o) = lp[0]; *(u16x4*)(Xl + o + 4) = lp[1];
    }
}

// zero the halo ring of two planar buffers
__global__ __launch_bounds__(256) void zero_halo_pl(
    u16* __restrict__ pa, u16* __restrict__ pb, int nGa, int nGb)
{
    const int p = blockIdx.x * 256 + threadIdx.x;
    if (p >= NPIXH) return;
    const int b = p / HP; const int rem = p - b * HP;
    const int hh = rem / 102, wp = rem - hh * 102;
    if (!((hh == 0) | (hh == 41) | (wp == 0) | (wp == 101))) return;
    const u16x4 z = {0, 0, 0, 0};
    for (int g = 0; g < nGa; ++g) {
        const size_t o = ((size_t)(b * nGa + g) * HPAD + rem) * 8;
        *(u16x4*)(pa + o) = z; *(u16x4*)(pa + o + 4) = z;
    }
    if (pb)
        for (int g = 0; g < nGb; ++g) {
            const size_t o = ((size_t)(b * nGb + g) * HPAD + rem) * 8;
            *(u16x4*)(pb + o) = z; *(u16x4*)(pb + o + 4) = z;
        }
}

// ---------------------------------------------------------------------------
// bf16-MFMA implicit-GEMM conv on planar-chunked haloed input.
// DBUF=0 (inst branch): r9-exact structure — unrolled pass loop (compile-time
//   useLo/Xsrc), inner 'unroll 1' ch loop, single 24 KB X buffer, two
//   barriers/chunk. NOW at BN=96 (FW=3, nN=2): 1.5x MFMA per LDS read; since
//   the kernel is LDS-read-bound, total LDS reads (and X re-fetch) drop 1/3.
// DBUF=1 (mask branch, SPLIT=1 only): r12 structure — 2x24 KB X dbuf,
//   stage(t+1) before step t's taps, ONE barrier/step.
// W: registers, tap-parity dbuf within a step (compile-time indices only);
// tap0 loaded directly at step start (no cross-step prefetch).
// PSTRIDE=384: plane LDS offset 6144 B == 0 mod 128 B (conflict-minimal).
// mfma(A=W, B=X): acc rows = channels (4/lane), cols = pixels.
// Grid: 1-D, XCD-bijective swizzle; nb (n-block) varies fastest.
// OUTMODE 0: planar hi+lo; 1: planar hi; 2: compact [m][CoutStore] f32.
// ---------------------------------------------------------------------------
template <int SPLIT, int BN, int NRS, int OUTMODE, int NCH, int MINW, int DBUF>
__global__ __launch_bounds__(256, MINW) void conv_mfma(
    const u16* __restrict__ Xhi, const u16* __restrict__ Xlo,
    const u16* __restrict__ Whi, const u16* __restrict__ Wlo,
    const float* __restrict__ bias,
    u16* __restrict__ Yhi, u16* __restrict__ Ylo, float* __restrict__ Yf,
    int Npad, int Cout, int CoutStore, int nGout, int do_relu,
    int nN, int cpx)
{
    constexpr int FW = BN / 32;          // n-frags per wave (wave covers BN/2 n)
    constexpr int PSTRIDE = 384;         // LDS plane stride: 6144 B, 128B-aligned
    constexpr int NGIN = NCH * 4;        // input planes per image
    constexpr int NPASS = (SPLIT == 3) ? 2 : 1;
    constexpr bool HASLO = (SPLIT == 3);
    constexpr int NBUF = DBUF ? 2 : 1;

    __shared__ u16 lsX[NBUF][4 * PSTRIDE * 8];   // 24 KB per buffer

    const int tid = threadIdx.x, lane = tid & 63, wid = tid >> 6;

    // XCD-bijective swizzle (nwg % 8 == 0 for all launches)
    const int pb_ = blockIdx.x;
    const int s = (pb_ & 7) * cpx + (pb_ >> 3);
    const int nb = s % nN;
    const int mt = s / nN;
    const int mb = mt & 31, bimg = mt >> 5;
    const int off = mb * 128;
    const int n0 = nb * BN;
    const int h0 = off / 100, w0 = off - h0 * 100;
    const int pTL0 = h0 * 102 + w0;

    const int wn = (wid & 1) * (BN / 2);
    const int wm = (wid >> 1) * 64;
    const int gA = lane >> 4, rA = lane & 15;
    const int wq0 = ((n0 + wn) >> 4) * 64;

    // per-lane pixel displacement for the 4 m-frags
    int pd[4]; bool mval[4];
    #pragma unroll
    for (int fb = 0; fb < 4; ++fb) {
        int mm = off + wm + fb * 16 + rA;
        mval[fb] = mm < HW;
        if (!mval[fb]) mm = HW - 1;
        const int h = mm / 100, w = mm - h * 100;
        pd[fb] = (h * 102 + w) - pTL0;
    }

    auto stageXp = [&](const u16* __restrict__ Xsrc, int ch, int bsel) {
        const size_t src = ((size_t)(bimg * NGIN + ch * 4 + wid) * HPAD + pTL0) * 8;
        char* dst = (char*)&lsX[bsel][0] + wid * (PSTRIDE * 16);
        #pragma unroll
        for (int i = 0; i < 6; ++i)
            gload_lds16(Xsrc + src + (size_t)(i * 64 + lane) * 8, dst + i * 1024);
    };

    s16x8 wh[2][FW];
    s16x8 wl[2][HASLO ? FW : 1];

    f32x4 acc[FW][4];
    #pragma unroll
    for (int i = 0; i < FW; ++i)
        #pragma unroll
        for (int j = 0; j < 4; ++j) acc[i][j] = (f32x4){0.f, 0.f, 0.f, 0.f};

    if constexpr (DBUF == 0) {
        // ===== r9-exact schedule: pass loop unrolled (compile-time useLo) =====
        #pragma unroll
        for (int pass = 0; pass < NPASS; ++pass) {
            const u16* Xsrc = (NPASS == 2 && pass == 1) ? Xlo : Xhi;
            const bool withLo = HASLO && (pass == 0);

            auto loadW = [&](int ch, int rs, int buf) {
                const size_t base = (((size_t)rs * NCH + ch) * (Npad * 4) + wq0 + lane) * 8;
                #pragma unroll
                for (int fa = 0; fa < FW; ++fa) {
                    wh[buf][fa] = *(const s16x8*)(Whi + base + fa * 64 * 8);
                    if constexpr (HASLO) {
                        if (withLo)
                            wl[buf][fa] = *(const s16x8*)(Wlo + base + fa * 64 * 8);
                    }
                }
            };

            #pragma unroll 1
            for (int ch = 0; ch < NCH; ++ch) {
                if (ch | pass) __syncthreads();   // protect LDS overwrite
                stageXp(Xsrc, ch, 0);
                loadW(ch, 0, 0);
                __syncthreads();                  // X tile ready (drains vmcnt)

                #pragma unroll
                for (int rs = 0; rs < NRS; ++rs) {
                    if (rs + 1 < NRS) loadW(ch, rs + 1, (rs + 1) & 1);
                    const int toff = (NRS == 9) ? ((rs / 3) * 102 + (rs % 3)) : 103;

                    s16x8 bX[4];
                    #pragma unroll
                    for (int fb = 0; fb < 4; ++fb) {
                        const int xi = (gA * PSTRIDE + pd[fb] + toff) * 8;
                        bX[fb] = *(const s16x8*)&lsX[0][xi];
                    }
                    #pragma unroll
                    for (int fa = 0; fa < FW; ++fa)
                        #pragma unroll
                        for (int fb = 0; fb < 4; ++fb) {
                            acc[fa][fb] = __builtin_amdgcn_mfma_f32_16x16x32_bf16(
                                wh[rs & 1][fa], bX[fb], acc[fa][fb], 0, 0, 0);
                            if constexpr (HASLO) {
                                if (pass == 0)
                                    acc[fa][fb] = __builtin_amdgcn_mfma_f32_16x16x32_bf16(
                                        wl[rs & 1][fa], bX[fb], acc[fa][fb], 0, 0, 0);
                            }
                        }
                }
            }
        }
    } else {
        // ===== r12 schedule (SPLIT=1 only here): X double-buffer =====
        constexpr int T = NPASS * NCH;

        auto loadW = [&](int step, int rs, int buf) {
            const int ch_ = (step >= NCH) ? step - NCH : step;
            const size_t base = (((size_t)rs * NCH + ch_) * (Npad * 4) + wq0 + lane) * 8;
            #pragma unroll
            for (int fa = 0; fa < FW; ++fa)
                wh[buf][fa] = *(const s16x8*)(Whi + base + fa * 64 * 8);
        };
        auto stageXs = [&](int step, int bsel) {
            const int ch_ = (step >= NCH) ? step - NCH : step;
            stageXp(Xhi, ch_, bsel);
        };

        stageXs(0, 0);
        __syncthreads();                  // buf0 ready

        #pragma unroll 1
        for (int t = 0; t < T; ++t) {
            const int cur = t & 1;
            loadW(t, 0, 0);               // before stageX: vmcnt-ordered
            if (t + 1 < T) stageXs(t + 1, cur ^ 1);

            #pragma unroll
            for (int rs = 0; rs < NRS; ++rs) {
                if (rs + 1 < NRS) loadW(t, rs + 1, (rs + 1) & 1);
                const int toff = (NRS == 9) ? ((rs / 3) * 102 + (rs % 3)) : 103;

                s16x8 bX[4];
                #pragma unroll
                for (int fb = 0; fb < 4; ++fb) {
                    const int xi = (gA * PSTRIDE + pd[fb] + toff) * 8;
                    bX[fb] = *(const s16x8*)&lsX[cur][xi];
                }
                #pragma unroll
                for (int fa = 0; fa < FW; ++fa)
                    #pragma unroll
                    for (int fb = 0; fb < 4; ++fb)
                        acc[fa][fb] = __builtin_amdgcn_mfma_f32_16x16x32_bf16(
                            wh[rs & 1][fa], bX[fb], acc[fa][fb], 0, 0, 0);
            }
            __syncthreads();   // buf[cur] free; buf[cur^1] loads landed
        }
    }

    // ---- epilogue ----
    #pragma unroll
    for (int fb = 0; fb < 4; ++fb) {
        if (!mval[fb]) continue;
        const int mm = off + wm + fb * 16 + rA;
        #pragma unroll
        for (int fa = 0; fa < FW; ++fa) {
            const int nbc = n0 + wn + fa * 16 + gA * 4;
            if (nbc >= CoutStore) continue;
            f32x4 v = acc[fa][fb];
            #pragma unroll
            for (int i = 0; i < 4; ++i) {
                const int n = nbc + i;
                float x = (n < Cout) ? (v[i] + bias[n]) : 0.f;
                if (do_relu) x = fmaxf(x, 0.f);
                v[i] = x;
            }
            if constexpr (OUTMODE == 2) {
                *(f32x4*)(Yf + (size_t)(bimg * HW + mm) * CoutStore + nbc) = v;
            } else {
                const size_t o =
                    ((size_t)(bimg * nGout + (nbc >> 3)) * HPAD + pTL0 + pd[fb] + 103) * 8 + (nbc & 7);
                u16x4 hp;
                #pragma unroll
                for (int i = 0; i < 4; ++i) hp[i] = f2bf(v[i]);
                *(u16x4*)(Yhi + o) = hp;
                if constexpr (OUTMODE == 0) {
                    u16x4 lp;
                    #pragma unroll
                    for (int i = 0; i < 4; ++i) lp[i] = f2bf(v[i] - bf2f(hp[i]));
                    *(u16x4*)(Ylo + o) = lp;
                }
            }
        }
    }
}

// ---------------------------------------------------------------------------
// iam conv: 4 outputs, 3x3, consumes planar hi+lo (fp32-equivalent), 20 planes
// ---------------------------------------------------------------------------
__global__ __launch_bounds__(256) void iam_conv_nhwc(
    const u16* __restrict__ fhi, const u16* __restrict__ flo,
    const float* __restrict__ Wt, const float* __restrict__ bias,
    float* __restrict__ iam)
{
    __shared__ float wsm[9 * 134 * 4];
    const int tid = threadIdx.x;
    for (int i = tid; i < 4824; i += 256) {
        const int rs = i / 536; const int rem = i - rs * 536;
        const int c = rem >> 2; const int n = rem & 3;
        wsm[i] = Wt[(n * 134 + c) * 9 + rs];
    }
    __syncthreads();
    const int m = blockIdx.x * 256 + tid;
    const int b = m / HW; const int hw = m - b * HW;
    const int h = hw / 100, w = hw - h * 100;
    const int pTL = h * 102 + w;
    float a0 = bias[0], a1 = bias[1], a2 = bias[2], a3 = bias[3];
    for (int rs = 0; rs < 9; ++rs) {
        const int pA = pTL + (rs / 3) * 102 + (rs % 3);
        const float* wrow = &wsm[rs * 536];
        for (int g = 0; g < 17; ++g) {
            const size_t o = ((size_t)(b * 20 + g) * HPAD + pA) * 8;
            s16x8 hv = *(const s16x8*)(fhi + o);
            s16x8 lv = *(const s16x8*)(flo + o);
            #pragma unroll
            for (int j = 0; j < 8; ++j) {
                const int c = g * 8 + j;
                if (c < 134) {
                    const float v = bf2f((u16)hv[j]) + bf2f((u16)lv[j]);
                    const float* wc = wrow + c * 4;
                    a0 = fmaf(v, wc[0], a0); a1 = fmaf(v, wc[1], a1);
                    a2 = fmaf(v, wc[2], a2); a3 = fmaf(v, wc[3], a3);
                }
            }
        }
    }
    iam[(b * 4 + 0) * HW + hw] = a0;
    iam[(b * 4 + 1) * HW + hw] = a1;
    iam[(b * 4 + 2) * HW + hw] = a2;
    iam[(b * 4 + 3) * HW + hw] = a3;
}

__device__ __forceinline__ float sigmoidf_dev(float x) {
    return 1.f / (1.f + expf(-x));
}

__global__ __launch_bounds__(256) void stats_kernel(
    const float* __restrict__ iam, int* __restrict__ pos, float* __restrict__ denom)
{
    const int i = blockIdx.x;
    const int tid = threadIdx.x;
    const float* p = &iam[i * HW];
    float bm = -1e30f; int bi = 0; float sum = 0.f;
    for (int l = tid; l < HW; l += 256) {
        const float s = sigmoidf_dev(p[l]);
        sum += s;
        if (s > bm) { bm = s; bi = l; }
    }
    __shared__ float sm[256]; __shared__ int si[256]; __shared__ float ss[256];
    sm[tid] = bm; si[tid] = bi; ss[tid] = sum;
    __syncthreads();
    for (int off = 128; off > 0; off >>= 1) {
        if (tid < off) {
            ss[tid] += ss[tid + off];
            const float m2 = sm[tid + off]; const int i2 = si[tid + off];
            if (m2 > sm[tid] || (m2 == sm[tid] && i2 < si[tid])) { sm[tid] = m2; si[tid] = i2; }
        }
        __syncthreads();
    }
    if (tid == 0) { pos[i] = si[0]; denom[i] = fmaxf(ss[0], 1e-6f); }
}

// inst[b][n][c] via planar hi+lo; grid (16 images, 17 planes)
__global__ __launch_bounds__(256) void inst_nhwc(
    const u16* __restrict__ fhi, const u16* __restrict__ flo,
    const float* __restrict__ iam, const float* __restrict__ denom,
    float* __restrict__ inst)
{
    const int b = blockIdx.x, g = blockIdx.y;
    const int tid = threadIdx.x;
    float acc[4][8] = {};
    const size_t pbase = (size_t)(b * 20 + g) * HPAD;
    for (int l = tid; l < HW; l += 256) {
        const int p = (l / 100 + 1) * 102 + (l % 100) + 1;
        s16x8 hv = *(const s16x8*)(fhi + (pbase + p) * 8);
        s16x8 lv = *(const s16x8*)(flo + (pbase + p) * 8);
        float fv[8];
        #pragma unroll
        for (int j = 0; j < 8; ++j) fv[j] = bf2f((u16)hv[j]) + bf2f((u16)lv[j]);
        #pragma unroll
        for (int n = 0; n < 4; ++n) {
            const float s = sigmoidf_dev(iam[(b * 4 + n) * HW + l]);
            #pragma unroll
            for (int j = 0; j < 8; ++j) acc[n][j] = fmaf(s, fv[j], acc[n][j]);
        }
    }
    __shared__ float red[128];
    const int lane = tid & 63, wid = tid >> 6;
    #pragma unroll
    for (int n = 0; n < 4; ++n)
        #pragma unroll
        for (int j = 0; j < 8; ++j) {
            float v = acc[n][j];
            #pragma unroll
            for (int off = 32; off > 0; off >>= 1) v += __shfl_xor(v, off);
            if (lane == 0) red[wid * 32 + n * 8 + j] = v;
        }
    __syncthreads();
    if (tid < 32) {
        const float s = red[tid] + red[32 + tid] + red[64 + tid] + red[96 + tid];
        const int n = tid >> 3, j = tid & 7;
        const int c = g * 8 + j;
        if (c < 134) inst[(b * 4 + n) * 134 + c] = s / denom[b * 4 + n];
    }
}

__global__ __launch_bounds__(128) void head_kernel(
    const float* __restrict__ inst,
    const float* __restrict__ cls_w, const float* __restrict__ cls_b,
    const float* __restrict__ mk_w, const float* __restrict__ mk_b,
    float* __restrict__ out_logits, float* __restrict__ pk)
{
    const int i = blockIdx.x;
    const int tid = threadIdx.x;
    __shared__ float iv[134];
    for (int c = tid; c < 134; c += 128) iv[c] = inst[i * 134 + c];
    __syncthreads();
    float a = mk_b[tid];
    for (int c = 0; c < 134; ++c) a = fmaf(iv[c], mk_w[tid * 134 + c], a);
    pk[i * 128 + tid] = a;
    if (tid < 2) {
        float g = cls_b[tid];
        for (int c = 0; c < 134; ++c) g = fmaf(iv[c], cls_w[tid * 134 + c], g);
        out_logits[i * 2 + tid] = g;
    }
}

__global__ void gather_nhwc(
    const u16* __restrict__ fhi, const u16* __restrict__ flo,
    const int* __restrict__ pos, float* __restrict__ outm, float* __restrict__ outr)
{
    const int i = blockIdx.x;
    const int c = threadIdx.x;
    if (c >= 134) return;
    const int p = pos[i];                          // batch-0 quirk preserved
    const int ph = (p / 100 + 1) * 102 + (p % 100) + 1;
    const size_t o = ((size_t)(c >> 3) * HPAD + ph) * 8 + (c & 7);   // b=0
    const float v = bf2f(fhi[o]) + bf2f(flo[o]);
    if (c < 67) outm[i * 67 + c] = v;
    else        outr[i * 67 + (c - 67)] = v;
}

// pred_masks from compact mf [m][128] f32
__global__ __launch_bounds__(256) void maskout_nhwc(
    const float* __restrict__ pk, const float* __restrict__ mf,
    float* __restrict__ outm)
{
    const int b = blockIdx.x, lc = blockIdx.y;
    const int tid = threadIdx.x;
    __shared__ float pks[4][128];
    for (int i = tid; i < 512; i += 256) pks[i >> 7][i & 127] = pk[b * 512 + i];
    __syncthreads();
    const int l = lc * 256 + tid;
    if (l >= HW) return;
    const float* row = mf + (size_t)(b * HW + l) * 128;
    float a[4] = {};
    for (int k = 0; k < 128; k += 4) {
        const f32x4 mv = *(const f32x4*)(row + k);
        #pragma unroll
        for (int n = 0; n < 4; ++n) {
            a[n] = fmaf(pks[n][k + 0], mv[0], a[n]);
            a[n] = fmaf(pks[n][k + 1], mv[1], a[n]);
            a[n] = fmaf(pks[n][k + 2], mv[2], a[n]);
            a[n] = fmaf(pks[n][k + 3], mv[3], a[n]);
        }
    }
    #pragma unroll
    for (int n = 0; n < 4; ++n) outm[(b * 4 + n) * HW + l] = a[n];
}

// ---------------------------------------------------------------------------
extern "C" void kernel_launch(void* const* d_in, const int* in_sizes, int n_in,
                              void* d_out, int out_size, void* d_ws, size_t ws_size,
                              hipStream_t stream)
{
    const float* features = (const float*)d_in[0];
    const float* iw0 = (const float*)d_in[1];
    const float* ib0 = (const float*)d_in[2];
    const float* iw1 = (const float*)d_in[3];
    const float* ib1 = (const float*)d_in[4];
    const float* iw2 = (const float*)d_in[5];
    const float* ib2 = (const float*)d_in[6];
    const float* iw3 = (const float*)d_in[7];
    const float* ib3 = (const float*)d_in[8];
    const float* iam_w = (const float*)d_in[9];
    const float* iam_b = (const float*)d_in[10];
    const float* cls_w = (const float*)d_in[11];
    const float* cls_b = (const float*)d_in[12];
    const float* mk_w = (const float*)d_in[13];
    const float* mk_b = (const float*)d_in[14];
    const float* mw0 = (const float*)d_in[15];
    const float* mb0 = (const float*)d_in[16];
    const float* mw1 = (const float*)d_in[17];
    const float* mb1 = (const float*)d_in[18];
    const float* mw2 = (const float*)d_in[19];
    const float* mb2 = (const float*)d_in[20];
    const float* mw3 = (const float*)d_in[21];
    const float* mb3 = (const float*)d_in[22];
    const float* pw = (const float*)d_in[23];
    const float* pb = (const float*)d_in[24];

    // weight image sizes (bytes): NRS*nCh*Npad*4*16  (inst Npad=192 for BN=96)
    constexpr size_t WI0 = (size_t)9 * 9 * 192 * 4 * 16;      // 995,328
    constexpr size_t WI123 = (size_t)9 * 5 * 192 * 4 * 16;    // 552,960
    constexpr size_t WM0 = (size_t)9 * 9 * 256 * 4 * 16;      // 1,327,104
    constexpr size_t WM123 = (size_t)9 * 8 * 256 * 4 * 16;    // 1,179,648
    constexpr size_t WPJ = (size_t)1 * 8 * 128 * 4 * 16;      // 65,536
    constexpr size_t PLANE = (size_t)HPAD * 16;               // 71,680 B
    constexpr size_t X0SZ = (size_t)16 * 36 * PLANE;          // 41,287,680
    constexpr size_t P20 = (size_t)16 * 20 * PLANE;           // 22,937,600

    char* ws = (char*)d_ws;
    size_t off = 0;
    auto carve = [&](size_t bytes) { char* p = ws + off; off += (bytes + 255) & ~(size_t)255; return p; };
    u16* wi0h = (u16*)carve(WI0); u16* wi0l = (u16*)carve(WI0);
    u16* wi1h = (u16*)carve(WI123); u16* wi1l = (u16*)carve(WI123);
    u16* wi2h = (u16*)carve(WI123); u16* wi2l = (u16*)carve(WI123);
    u16* wi3h = (u16*)carve(WI123); u16* wi3l = (u16*)carve(WI123);
    u16* wm0h = (u16*)carve(WM0);
    u16* wm1h = (u16*)carve(WM123); u16* wm2h = (u16*)carve(WM123); u16* wm3h = (u16*)carve(WM123);
    u16* wpjh = (u16*)carve(WPJ);
    u16* X0hi = (u16*)carve(X0SZ);
    char* RGA = carve(X0SZ);        // X0lo -> MBhi
    char* RGB = carve(2 * P20);     // RAhi+RAlo -> MAhi
    char* RGC = carve(2 * P20);     // RBhi+RBlo -> mf
    float* iamb = (float*)carve(1024000);
    int* pos = (int*)carve(256);
    float* denom = (float*)carve(256);
    float* instb = (float*)carve(34560);
    float* pkbuf = (float*)carve(32768);

    u16* X0lo = (u16*)RGA;
    u16* MBhi = (u16*)RGA;
    u16* RAhi = (u16*)RGB; u16* RAlo = (u16*)(RGB + P20);
    u16* MAhi = (u16*)RGB;
    u16* RBhi = (u16*)RGC; u16* RBlo = (u16*)(RGC + P20);
    float* mf = (float*)RGC;

    float* out_logits = (float*)d_out;          // 64*2
    float* out_mask = out_logits + 128;         // 64*67
    float* out_reg = out_mask + 64 * 67;        // 64*67
    float* out_masks = out_reg + 64 * 67;       // 64*4000

    const dim3 blk(256);
    auto rp = [&](const float* W, u16* h, u16* l, int Cout_, int Cin_, int NRS_,
                  int nCh_, int Npad_, int dolo) {
        const int tot = NRS_ * nCh_ * Npad_ * 4;
        repack_w<<<dim3((tot + 255) / 256), blk, 0, stream>>>(W, h, l, Cout_, Cin_, NRS_, nCh_, Npad_, dolo);
    };
    rp(iw0, wi0h, wi0l, 134, 258, 9, 9, 192, 1);
    rp(iw1, wi1h, wi1l, 134, 134, 9, 5, 192, 1);
    rp(iw2, wi2h, wi2l, 134, 134, 9, 5, 192, 1);
    rp(iw3, wi3h, wi3l, 134, 134, 9, 5, 192, 1);
    rp(mw0, wm0h, nullptr, 256, 258, 9, 9, 256, 0);
    rp(mw1, wm1h, nullptr, 256, 256, 9, 8, 256, 0);
    rp(mw2, wm2h, nullptr, 256, 256, 9, 8, 256, 0);
    rp(mw3, wm3h, nullptr, 256, 256, 9, 8, 256, 0);
    rp(pw, wpjh, nullptr, 128, 256, 1, 8, 128, 0);

    const dim3 gH((NPIXH + 255) / 256);
    prep_x0<<<gH, blk, 0, stream>>>(features, X0hi, X0lo);
    zero_halo_pl<<<gH, blk, 0, stream>>>(RAhi, RAlo, 20, 20);

    // ---- inst branch: SPLIT=3 pass-split, single-buffer, BN=96 (FW=3), nN=2 ----
    // nwg = 2*32*16 = 1024, cpx = 128; MINW=3 (reg cap 170, ~140 used)
    conv_mfma<3, 96, 9, 0, 9, 3, 0><<<dim3(1024), blk, 0, stream>>>(
        X0hi, X0lo, wi0h, wi0l, ib0, RAhi, RAlo, nullptr, 192, 134, 160, 20, 1, 2, 128);
    zero_halo_pl<<<gH, blk, 0, stream>>>(RBhi, RBlo, 20, 20);
    conv_mfma<3, 96, 9, 0, 5, 3, 0><<<dim3(1024), blk, 0, stream>>>(
        RAhi, RAlo, wi1h, wi1l, ib1, RBhi, RBlo, nullptr, 192, 134, 160, 20, 1, 2, 128);
    conv_mfma<3, 96, 9, 0, 5, 3, 0><<<dim3(1024), blk, 0, stream>>>(
        RBhi, RBlo, wi2h, wi2l, ib2, RAhi, RAlo, nullptr, 192, 134, 160, 20, 1, 2, 128);
    conv_mfma<3, 96, 9, 0, 5, 3, 0><<<dim3(1024), blk, 0, stream>>>(
        RAhi, RAlo, wi3h, wi3l, ib3, RBhi, RBlo, nullptr, 192, 134, 160, 20, 1, 2, 128);

    iam_conv_nhwc<<<dim3(250), blk, 0, stream>>>(RBhi, RBlo, iam_w, iam_b, iamb);
    stats_kernel<<<dim3(64), blk, 0, stream>>>(iamb, pos, denom);
    inst_nhwc<<<dim3(16, 17), blk, 0, stream>>>(RBhi, RBlo, iamb, denom, instb);
    head_kernel<<<dim3(64), dim3(128), 0, stream>>>(instb, cls_w, cls_b, mk_w, mk_b, out_logits, pkbuf);
    gather_nhwc<<<dim3(64), dim3(192), 0, stream>>>(RBhi, RBlo, pos, out_mask, out_reg);

    // ---- mask branch: SPLIT=1 double-buffer (r12), BN=128, nN=2, MINW=3 ----
    // nwg = 2*32*16 = 1024, cpx = 128
    zero_halo_pl<<<gH, blk, 0, stream>>>(MAhi, MBhi, 32, 32);
    conv_mfma<1, 128, 9, 1, 9, 3, 1><<<dim3(1024), blk, 0, stream>>>(
        X0hi, nullptr, wm0h, nullptr, mb0, MAhi, nullptr, nullptr, 256, 256, 256, 32, 1, 2, 128);
    conv_mfma<1, 128, 9, 1, 8, 3, 1><<<dim3(1024), blk, 0, stream>>>(
        MAhi, nullptr, wm1h, nullptr, mb1, MBhi, nullptr, nullptr, 256, 256, 256, 32, 1, 2, 128);
    conv_mfma<1, 128, 9, 1, 8, 3, 1><<<dim3(1024), blk, 0, stream>>>(
        MBhi, nullptr, wm2h, nullptr, mb2, MAhi, nullptr, nullptr, 256, 256, 256, 32, 1, 2, 128);
    conv_mfma<1, 128, 9, 1, 8, 3, 1><<<dim3(1024), blk, 0, stream>>>(
        MAhi, nullptr, wm3h, nullptr, mb3, MBhi, nullptr, nullptr, 256, 256, 256, 32, 1, 2, 128);
    // proj 1x1: BN=128, nN=1 -> nwg=512, cpx=64
    conv_mfma<1, 128, 1, 2, 8, 3, 1><<<dim3(512), blk, 0, stream>>>(
        MBhi, nullptr, wpjh, nullptr, pb, nullptr, nullptr, mf, 128, 128, 128, 0, 0, 1, 64);

    maskout_nhwc<<<dim3(16, 16), blk, 0, stream>>>(pkbuf, mf, out_masks);
}

// Round 16
// 1105.036 us; speedup vs baseline: 1.0666x; 1.0666x over previous
//
#include <hip/hip_runtime.h>
#include <hip/hip_bf16.h>
#include <math.h>

constexpr int HW = 4000;
constexpr int HP = 4284;            // haloed pixels per image (42*102)
constexpr int HPAD = 4480;          // plane stride in pixels (incl. staging slack)
constexpr int NPIXH = 16 * HP;      // 68544

typedef short s16x8 __attribute__((ext_vector_type(8)));
typedef float f32x4 __attribute__((ext_vector_type(4)));
typedef unsigned short u16x4 __attribute__((ext_vector_type(4)));
typedef unsigned short u16;

__device__ __forceinline__ u16 f2bf(float f) {
    __hip_bfloat16 h = __float2bfloat16(f);
    u16 b; __builtin_memcpy(&b, &h, 2); return b;
}
__device__ __forceinline__ float bf2f(u16 b) {
    __hip_bfloat16 h; __builtin_memcpy(&h, &b, 2); return __bfloat162float(h);
}

__device__ __forceinline__ void gload_lds16(const void* g, void* l) {
    __builtin_amdgcn_global_load_lds(
        (const __attribute__((address_space(1))) void*)g,
        (__attribute__((address_space(3))) void*)l, 16, 0, 0);
}

// ---------------------------------------------------------------------------
// Weight repack: OIHW fp32 -> [rs][ch][Npad*4 chunks][8] bf16 hi (+ lo).
// chunk q: f=q>>6, g=(q>>4)&3, rA=q&15 -> n=f*16+rA, c=ch*32+g*8+j
// ---------------------------------------------------------------------------
__global__ __launch_bounds__(256) void repack_w(
    const float* __restrict__ W, u16* __restrict__ Wh, u16* __restrict__ Wl,
    int Cout, int Cin, int NRS, int nCh, int Npad, int do_lo)
{
    const int chunk = blockIdx.x * 256 + threadIdx.x;
    const int per = Npad * 4;
    const int total = NRS * nCh * per;
    if (chunk >= total) return;
    const int q = chunk % per;
    const int t2 = chunk / per;
    const int ch = t2 % nCh;
    const int rs = t2 / nCh;
    const int f = q >> 6, g = (q >> 4) & 3, rA = q & 15;
    const int n = f * 16 + rA;
    u16x4 hp[2], lp[2];
    #pragma unroll
    for (int j = 0; j < 8; ++j) {
        const int c = ch * 32 + g * 8 + j;
        const float v = (n < Cout && c < Cin) ? W[((size_t)n * Cin + c) * NRS + rs] : 0.f;
        const u16 hb = f2bf(v);
        hp[j >> 2][j & 3] = hb;
        lp[j >> 2][j & 3] = f2bf(v - bf2f(hb));
    }
    const size_t o = (size_t)chunk * 8;
    *(u16x4*)(Wh + o) = hp[0]; *(u16x4*)(Wh + o + 4) = hp[1];
    if (do_lo) { *(u16x4*)(Wl + o) = lp[0]; *(u16x4*)(Wl + o + 4) = lp[1]; }
}

// ---------------------------------------------------------------------------
// features NCHW fp32 -> planar-chunked haloed bf16 hi+lo (36 planes of 8 ch)
// channels: 0=x, 1=y, 2..257=f, 258..287=0
// ---------------------------------------------------------------------------
__global__ __launch_bounds__(256) void prep_x0(
    const float* __restrict__ feat, u16* __restrict__ Xh, u16* __restrict__ Xl)
{
    const int p = blockIdx.x * 256 + threadIdx.x;
    if (p >= NPIXH) return;
    const int b = p / HP; const int rem = p - b * HP;
    const int hh = rem / 102, wp = rem - hh * 102;
    const bool halo = (hh == 0) | (hh == 41) | (wp == 0) | (wp == 101);
    const int h = hh - 1, w = wp - 1;
    const int hw = h * 100 + w;
    const float xw = -1.f + 2.f * (float)w / 99.f;
    const float yh = -1.f + 2.f * (float)h / 39.f;
    for (int g = 0; g < 36; ++g) {
        u16x4 hp[2], lp[2];
        #pragma unroll
        for (int j = 0; j < 8; ++j) {
            const int c = g * 8 + j;
            float v = 0.f;
            if (!halo) {
                if (c == 0) v = xw;
                else if (c == 1) v = yh;
                else if (c < 258) v = feat[((size_t)(b * 256 + (c - 2))) * HW + hw];
            }
            const u16 hb = f2bf(v);
            hp[j >> 2][j & 3] = hb;
            lp[j >> 2][j & 3] = f2bf(v - bf2f(hb));
        }
        const size_t o = ((size_t)(b * 36 + g) * HPAD + rem) * 8;
        *(u16x4*)(Xh + o) = hp[0]; *(u16x4*)(Xh + o + 4) = hp[1];
        *(u16x4*)(Xl + o) = lp[0]; *(u16x4*)(Xl + o + 4) = lp[1];
    }
}

// zero the halo ring of two planar buffers
__global__ __launch_bounds__(256) void zero_halo_pl(
    u16* __restrict__ pa, u16* __restrict__ pb, int nGa, int nGb)
{
    const int p = blockIdx.x * 256 + threadIdx.x;
    if (p >= NPIXH) return;
    const int b = p / HP; const int rem = p - b * HP;
    const int hh = rem / 102, wp = rem - hh * 102;
    if (!((hh == 0) | (hh == 41) | (wp == 0) | (wp == 101))) return;
    const u16x4 z = {0, 0, 0, 0};
    for (int g = 0; g < nGa; ++g) {
        const size_t o = ((size_t)(b * nGa + g) * HPAD + rem) * 8;
        *(u16x4*)(pa + o) = z; *(u16x4*)(pa + o + 4) = z;
    }
    if (pb)
        for (int g = 0; g < nGb; ++g) {
            const size_t o = ((size_t)(b * nGb + g) * HPAD + rem) * 8;
            *(u16x4*)(pb + o) = z; *(u16x4*)(pb + o + 4) = z;
        }
}

// ---------------------------------------------------------------------------
// bf16-MFMA implicit-GEMM conv on planar-chunked haloed input.
// DBUF=0 (inst branch): EXACT r9 structure — nested '#pragma unroll' pass
//   loop (pass/useLo/Xsrc compile-time per copy), inner 'unroll 1' ch loop,
//   single 24 KB X buffer, two barriers/chunk. Best measured: 164 us.
// DBUF=1 (mask branch, SPLIT=1 only): r12 structure — 2x24 KB X dbuf,
//   stage(t+1) before step t's taps, ONE barrier/step.
// W: registers, tap-parity dbuf within a step (compile-time indices only);
// tap0 loaded directly at step start (no cross-step prefetch).
// PSTRIDE=384: plane LDS offset 6144 B == 0 mod 128 B (conflict-minimal).
// mfma(A=W, B=X): acc rows = channels (4/lane), cols = pixels.
// Grid: 1-D, XCD-bijective swizzle; nb (n-block) varies fastest.
// OUTMODE 0: planar hi+lo; 1: planar hi; 2: compact [m][CoutStore] f32.
// NOTE (r15): BN=96/FW=3 measured WORSE (217us, occ 24%) — occupancy/latency
// hiding dominates LDS-read ratio for this shape. BN=64/nN=3 is the optimum.
// ---------------------------------------------------------------------------
template <int SPLIT, int BN, int NRS, int OUTMODE, int NCH, int MINW, int DBUF>
__global__ __launch_bounds__(256, MINW) void conv_mfma(
    const u16* __restrict__ Xhi, const u16* __restrict__ Xlo,
    const u16* __restrict__ Whi, const u16* __restrict__ Wlo,
    const float* __restrict__ bias,
    u16* __restrict__ Yhi, u16* __restrict__ Ylo, float* __restrict__ Yf,
    int Npad, int Cout, int CoutStore, int nGout, int do_relu,
    int nN, int cpx)
{
    constexpr int FW = BN / 32;          // n-frags per wave (wave covers BN/2 n)
    constexpr int PSTRIDE = 384;         // LDS plane stride: 6144 B, 128B-aligned
    constexpr int NGIN = NCH * 4;        // input planes per image
    constexpr int NPASS = (SPLIT == 3) ? 2 : 1;
    constexpr bool HASLO = (SPLIT == 3);
    constexpr int NBUF = DBUF ? 2 : 1;

    __shared__ u16 lsX[NBUF][4 * PSTRIDE * 8];   // 24 KB per buffer

    const int tid = threadIdx.x, lane = tid & 63, wid = tid >> 6;

    // XCD-bijective swizzle (nwg % 8 == 0 for all launches)
    const int pb_ = blockIdx.x;
    const int s = (pb_ & 7) * cpx + (pb_ >> 3);
    const int nb = s % nN;
    const int mt = s / nN;
    const int mb = mt & 31, bimg = mt >> 5;
    const int off = mb * 128;
    const int n0 = nb * BN;
    const int h0 = off / 100, w0 = off - h0 * 100;
    const int pTL0 = h0 * 102 + w0;

    const int wn = (wid & 1) * (BN / 2);
    const int wm = (wid >> 1) * 64;
    const int gA = lane >> 4, rA = lane & 15;
    const int wq0 = ((n0 + wn) >> 4) * 64;

    // per-lane pixel displacement for the 4 m-frags
    int pd[4]; bool mval[4];
    #pragma unroll
    for (int fb = 0; fb < 4; ++fb) {
        int mm = off + wm + fb * 16 + rA;
        mval[fb] = mm < HW;
        if (!mval[fb]) mm = HW - 1;
        const int h = mm / 100, w = mm - h * 100;
        pd[fb] = (h * 102 + w) - pTL0;
    }

    auto stageXp = [&](const u16* __restrict__ Xsrc, int ch, int bsel) {
        const size_t src = ((size_t)(bimg * NGIN + ch * 4 + wid) * HPAD + pTL0) * 8;
        char* dst = (char*)&lsX[bsel][0] + wid * (PSTRIDE * 16);
        #pragma unroll
        for (int i = 0; i < 6; ++i)
            gload_lds16(Xsrc + src + (size_t)(i * 64 + lane) * 8, dst + i * 1024);
    };

    s16x8 wh[2][FW];
    s16x8 wl[2][HASLO ? FW : 1];

    f32x4 acc[FW][4];
    #pragma unroll
    for (int i = 0; i < FW; ++i)
        #pragma unroll
        for (int j = 0; j < 4; ++j) acc[i][j] = (f32x4){0.f, 0.f, 0.f, 0.f};

    if constexpr (DBUF == 0) {
        // ===== r9-exact schedule: pass loop unrolled (compile-time useLo) =====
        #pragma unroll
        for (int pass = 0; pass < NPASS; ++pass) {
            const u16* Xsrc = (NPASS == 2 && pass == 1) ? Xlo : Xhi;
            const bool withLo = HASLO && (pass == 0);

            auto loadW = [&](int ch, int rs, int buf) {
                const size_t base = (((size_t)rs * NCH + ch) * (Npad * 4) + wq0 + lane) * 8;
                #pragma unroll
                for (int fa = 0; fa < FW; ++fa) {
                    wh[buf][fa] = *(const s16x8*)(Whi + base + fa * 64 * 8);
                    if constexpr (HASLO) {
                        if (withLo)
                            wl[buf][fa] = *(const s16x8*)(Wlo + base + fa * 64 * 8);
                    }
                }
            };

            #pragma unroll 1
            for (int ch = 0; ch < NCH; ++ch) {
                if (ch | pass) __syncthreads();   // protect LDS overwrite
                stageXp(Xsrc, ch, 0);
                loadW(ch, 0, 0);
                __syncthreads();                  // X tile ready (drains vmcnt)

                #pragma unroll
                for (int rs = 0; rs < NRS; ++rs) {
                    if (rs + 1 < NRS) loadW(ch, rs + 1, (rs + 1) & 1);
                    const int toff = (NRS == 9) ? ((rs / 3) * 102 + (rs % 3)) : 103;

                    s16x8 bX[4];
                    #pragma unroll
                    for (int fb = 0; fb < 4; ++fb) {
                        const int xi = (gA * PSTRIDE + pd[fb] + toff) * 8;
                        bX[fb] = *(const s16x8*)&lsX[0][xi];
                    }
                    #pragma unroll
                    for (int fa = 0; fa < FW; ++fa)
                        #pragma unroll
                        for (int fb = 0; fb < 4; ++fb) {
                            acc[fa][fb] = __builtin_amdgcn_mfma_f32_16x16x32_bf16(
                                wh[rs & 1][fa], bX[fb], acc[fa][fb], 0, 0, 0);
                            if constexpr (HASLO) {
                                if (pass == 0)
                                    acc[fa][fb] = __builtin_amdgcn_mfma_f32_16x16x32_bf16(
                                        wl[rs & 1][fa], bX[fb], acc[fa][fb], 0, 0, 0);
                            }
                        }
                }
            }
        }
    } else {
        // ===== r12 schedule (SPLIT=1 only here): X double-buffer =====
        constexpr int T = NPASS * NCH;

        auto loadW = [&](int step, int rs, int buf) {
            const int ch_ = (step >= NCH) ? step - NCH : step;
            const size_t base = (((size_t)rs * NCH + ch_) * (Npad * 4) + wq0 + lane) * 8;
            #pragma unroll
            for (int fa = 0; fa < FW; ++fa)
                wh[buf][fa] = *(const s16x8*)(Whi + base + fa * 64 * 8);
        };
        auto stageXs = [&](int step, int bsel) {
            const int ch_ = (step >= NCH) ? step - NCH : step;
            stageXp(Xhi, ch_, bsel);
        };

        stageXs(0, 0);
        __syncthreads();                  // buf0 ready

        #pragma unroll 1
        for (int t = 0; t < T; ++t) {
            const int cur = t & 1;
            loadW(t, 0, 0);               // before stageX: vmcnt-ordered
            if (t + 1 < T) stageXs(t + 1, cur ^ 1);

            #pragma unroll
            for (int rs = 0; rs < NRS; ++rs) {
                if (rs + 1 < NRS) loadW(t, rs + 1, (rs + 1) & 1);
                const int toff = (NRS == 9) ? ((rs / 3) * 102 + (rs % 3)) : 103;

                s16x8 bX[4];
                #pragma unroll
                for (int fb = 0; fb < 4; ++fb) {
                    const int xi = (gA * PSTRIDE + pd[fb] + toff) * 8;
                    bX[fb] = *(const s16x8*)&lsX[cur][xi];
                }
                #pragma unroll
                for (int fa = 0; fa < FW; ++fa)
                    #pragma unroll
                    for (int fb = 0; fb < 4; ++fb)
                        acc[fa][fb] = __builtin_amdgcn_mfma_f32_16x16x32_bf16(
                            wh[rs & 1][fa], bX[fb], acc[fa][fb], 0, 0, 0);
            }
            __syncthreads();   // buf[cur] free; buf[cur^1] loads landed
        }
    }

    // ---- epilogue ----
    #pragma unroll
    for (int fb = 0; fb < 4; ++fb) {
        if (!mval[fb]) continue;
        const int mm = off + wm + fb * 16 + rA;
        #pragma unroll
        for (int fa = 0; fa < FW; ++fa) {
            const int nbc = n0 + wn + fa * 16 + gA * 4;
            if (nbc >= CoutStore) continue;
            f32x4 v = acc[fa][fb];
            #pragma unroll
            for (int i = 0; i < 4; ++i) {
                const int n = nbc + i;
                float x = (n < Cout) ? (v[i] + bias[n]) : 0.f;
                if (do_relu) x = fmaxf(x, 0.f);
                v[i] = x;
            }
            if constexpr (OUTMODE == 2) {
                *(f32x4*)(Yf + (size_t)(bimg * HW + mm) * CoutStore + nbc) = v;
            } else {
                const size_t o =
                    ((size_t)(bimg * nGout + (nbc >> 3)) * HPAD + pTL0 + pd[fb] + 103) * 8 + (nbc & 7);
                u16x4 hp;
                #pragma unroll
                for (int i = 0; i < 4; ++i) hp[i] = f2bf(v[i]);
                *(u16x4*)(Yhi + o) = hp;
                if constexpr (OUTMODE == 0) {
                    u16x4 lp;
                    #pragma unroll
                    for (int i = 0; i < 4; ++i) lp[i] = f2bf(v[i] - bf2f(hp[i]));
                    *(u16x4*)(Ylo + o) = lp;
                }
            }
        }
    }
}

// ---------------------------------------------------------------------------
// iam conv: 4 outputs, 3x3, consumes planar hi+lo (fp32-equivalent), 20 planes
// ---------------------------------------------------------------------------
__global__ __launch_bounds__(256) void iam_conv_nhwc(
    const u16* __restrict__ fhi, const u16* __restrict__ flo,
    const float* __restrict__ Wt, const float* __restrict__ bias,
    float* __restrict__ iam)
{
    __shared__ float wsm[9 * 134 * 4];
    const int tid = threadIdx.x;
    for (int i = tid; i < 4824; i += 256) {
        const int rs = i / 536; const int rem = i - rs * 536;
        const int c = rem >> 2; const int n = rem & 3;
        wsm[i] = Wt[(n * 134 + c) * 9 + rs];
    }
    __syncthreads();
    const int m = blockIdx.x * 256 + tid;
    const int b = m / HW; const int hw = m - b * HW;
    const int h = hw / 100, w = hw - h * 100;
    const int pTL = h * 102 + w;
    float a0 = bias[0], a1 = bias[1], a2 = bias[2], a3 = bias[3];
    for (int rs = 0; rs < 9; ++rs) {
        const int pA = pTL + (rs / 3) * 102 + (rs % 3);
        const float* wrow = &wsm[rs * 536];
        for (int g = 0; g < 17; ++g) {
            const size_t o = ((size_t)(b * 20 + g) * HPAD + pA) * 8;
            s16x8 hv = *(const s16x8*)(fhi + o);
            s16x8 lv = *(const s16x8*)(flo + o);
            #pragma unroll
            for (int j = 0; j < 8; ++j) {
                const int c = g * 8 + j;
                if (c < 134) {
                    const float v = bf2f((u16)hv[j]) + bf2f((u16)lv[j]);
                    const float* wc = wrow + c * 4;
                    a0 = fmaf(v, wc[0], a0); a1 = fmaf(v, wc[1], a1);
                    a2 = fmaf(v, wc[2], a2); a3 = fmaf(v, wc[3], a3);
                }
            }
        }
    }
    iam[(b * 4 + 0) * HW + hw] = a0;
    iam[(b * 4 + 1) * HW + hw] = a1;
    iam[(b * 4 + 2) * HW + hw] = a2;
    iam[(b * 4 + 3) * HW + hw] = a3;
}

__device__ __forceinline__ float sigmoidf_dev(float x) {
    return 1.f / (1.f + expf(-x));
}

__global__ __launch_bounds__(256) void stats_kernel(
    const float* __restrict__ iam, int* __restrict__ pos, float* __restrict__ denom)
{
    const int i = blockIdx.x;
    const int tid = threadIdx.x;
    const float* p = &iam[i * HW];
    float bm = -1e30f; int bi = 0; float sum = 0.f;
    for (int l = tid; l < HW; l += 256) {
        const float s = sigmoidf_dev(p[l]);
        sum += s;
        if (s > bm) { bm = s; bi = l; }
    }
    __shared__ float sm[256]; __shared__ int si[256]; __shared__ float ss[256];
    sm[tid] = bm; si[tid] = bi; ss[tid] = sum;
    __syncthreads();
    for (int off = 128; off > 0; off >>= 1) {
        if (tid < off) {
            ss[tid] += ss[tid + off];
            const float m2 = sm[tid + off]; const int i2 = si[tid + off];
            if (m2 > sm[tid] || (m2 == sm[tid] && i2 < si[tid])) { sm[tid] = m2; si[tid] = i2; }
        }
        __syncthreads();
    }
    if (tid == 0) { pos[i] = si[0]; denom[i] = fmaxf(ss[0], 1e-6f); }
}

// inst[b][n][c] via planar hi+lo; grid (16 images, 17 planes)
__global__ __launch_bounds__(256) void inst_nhwc(
    const u16* __restrict__ fhi, const u16* __restrict__ flo,
    const float* __restrict__ iam, const float* __restrict__ denom,
    float* __restrict__ inst)
{
    const int b = blockIdx.x, g = blockIdx.y;
    const int tid = threadIdx.x;
    float acc[4][8] = {};
    const size_t pbase = (size_t)(b * 20 + g) * HPAD;
    for (int l = tid; l < HW; l += 256) {
        const int p = (l / 100 + 1) * 102 + (l % 100) + 1;
        s16x8 hv = *(const s16x8*)(fhi + (pbase + p) * 8);
        s16x8 lv = *(const s16x8*)(flo + (pbase + p) * 8);
        float fv[8];
        #pragma unroll
        for (int j = 0; j < 8; ++j) fv[j] = bf2f((u16)hv[j]) + bf2f((u16)lv[j]);
        #pragma unroll
        for (int n = 0; n < 4; ++n) {
            const float s = sigmoidf_dev(iam[(b * 4 + n) * HW + l]);
            #pragma unroll
            for (int j = 0; j < 8; ++j) acc[n][j] = fmaf(s, fv[j], acc[n][j]);
        }
    }
    __shared__ float red[128];
    const int lane = tid & 63, wid = tid >> 6;
    #pragma unroll
    for (int n = 0; n < 4; ++n)
        #pragma unroll
        for (int j = 0; j < 8; ++j) {
            float v = acc[n][j];
            #pragma unroll
            for (int off = 32; off > 0; off >>= 1) v += __shfl_xor(v, off);
            if (lane == 0) red[wid * 32 + n * 8 + j] = v;
        }
    __syncthreads();
    if (tid < 32) {
        const float s = red[tid] + red[32 + tid] + red[64 + tid] + red[96 + tid];
        const int n = tid >> 3, j = tid & 7;
        const int c = g * 8 + j;
        if (c < 134) inst[(b * 4 + n) * 134 + c] = s / denom[b * 4 + n];
    }
}

__global__ __launch_bounds__(128) void head_kernel(
    const float* __restrict__ inst,
    const float* __restrict__ cls_w, const float* __restrict__ cls_b,
    const float* __restrict__ mk_w, const float* __restrict__ mk_b,
    float* __restrict__ out_logits, float* __restrict__ pk)
{
    const int i = blockIdx.x;
    const int tid = threadIdx.x;
    __shared__ float iv[134];
    for (int c = tid; c < 134; c += 128) iv[c] = inst[i * 134 + c];
    __syncthreads();
    float a = mk_b[tid];
    for (int c = 0; c < 134; ++c) a = fmaf(iv[c], mk_w[tid * 134 + c], a);
    pk[i * 128 + tid] = a;
    if (tid < 2) {
        float g = cls_b[tid];
        for (int c = 0; c < 134; ++c) g = fmaf(iv[c], cls_w[tid * 134 + c], g);
        out_logits[i * 2 + tid] = g;
    }
}

__global__ void gather_nhwc(
    const u16* __restrict__ fhi, const u16* __restrict__ flo,
    const int* __restrict__ pos, float* __restrict__ outm, float* __restrict__ outr)
{
    const int i = blockIdx.x;
    const int c = threadIdx.x;
    if (c >= 134) return;
    const int p = pos[i];                          // batch-0 quirk preserved
    const int ph = (p / 100 + 1) * 102 + (p % 100) + 1;
    const size_t o = ((size_t)(c >> 3) * HPAD + ph) * 8 + (c & 7);   // b=0
    const float v = bf2f(fhi[o]) + bf2f(flo[o]);
    if (c < 67) outm[i * 67 + c] = v;
    else        outr[i * 67 + (c - 67)] = v;
}

// pred_masks from compact mf [m][128] f32
__global__ __launch_bounds__(256) void maskout_nhwc(
    const float* __restrict__ pk, const float* __restrict__ mf,
    float* __restrict__ outm)
{
    const int b = blockIdx.x, lc = blockIdx.y;
    const int tid = threadIdx.x;
    __shared__ float pks[4][128];
    for (int i = tid; i < 512; i += 256) pks[i >> 7][i & 127] = pk[b * 512 + i];
    __syncthreads();
    const int l = lc * 256 + tid;
    if (l >= HW) return;
    const float* row = mf + (size_t)(b * HW + l) * 128;
    float a[4] = {};
    for (int k = 0; k < 128; k += 4) {
        const f32x4 mv = *(const f32x4*)(row + k);
        #pragma unroll
        for (int n = 0; n < 4; ++n) {
            a[n] = fmaf(pks[n][k + 0], mv[0], a[n]);
            a[n] = fmaf(pks[n][k + 1], mv[1], a[n]);
            a[n] = fmaf(pks[n][k + 2], mv[2], a[n]);
            a[n] = fmaf(pks[n][k + 3], mv[3], a[n]);
        }
    }
    #pragma unroll
    for (int n = 0; n < 4; ++n) outm[(b * 4 + n) * HW + l] = a[n];
}

// ---------------------------------------------------------------------------
extern "C" void kernel_launch(void* const* d_in, const int* in_sizes, int n_in,
                              void* d_out, int out_size, void* d_ws, size_t ws_size,
                              hipStream_t stream)
{
    const float* features = (const float*)d_in[0];
    const float* iw0 = (const float*)d_in[1];
    const float* ib0 = (const float*)d_in[2];
    const float* iw1 = (const float*)d_in[3];
    const float* ib1 = (const float*)d_in[4];
    const float* iw2 = (const float*)d_in[5];
    const float* ib2 = (const float*)d_in[6];
    const float* iw3 = (const float*)d_in[7];
    const float* ib3 = (const float*)d_in[8];
    const float* iam_w = (const float*)d_in[9];
    const float* iam_b = (const float*)d_in[10];
    const float* cls_w = (const float*)d_in[11];
    const float* cls_b = (const float*)d_in[12];
    const float* mk_w = (const float*)d_in[13];
    const float* mk_b = (const float*)d_in[14];
    const float* mw0 = (const float*)d_in[15];
    const float* mb0 = (const float*)d_in[16];
    const float* mw1 = (const float*)d_in[17];
    const float* mb1 = (const float*)d_in[18];
    const float* mw2 = (const float*)d_in[19];
    const float* mb2 = (const float*)d_in[20];
    const float* mw3 = (const float*)d_in[21];
    const float* mb3 = (const float*)d_in[22];
    const float* pw = (const float*)d_in[23];
    const float* pb = (const float*)d_in[24];

    // weight image sizes (bytes): NRS*nCh*Npad*4*16
    constexpr size_t WI0 = (size_t)9 * 9 * 160 * 4 * 16;      // 829,440
    constexpr size_t WI123 = (size_t)9 * 5 * 160 * 4 * 16;    // 460,800
    constexpr size_t WM0 = (size_t)9 * 9 * 256 * 4 * 16;      // 1,327,104
    constexpr size_t WM123 = (size_t)9 * 8 * 256 * 4 * 16;    // 1,179,648
    constexpr size_t WPJ = (size_t)1 * 8 * 128 * 4 * 16;      // 65,536
    constexpr size_t PLANE = (size_t)HPAD * 16;               // 71,680 B
    constexpr size_t X0SZ = (size_t)16 * 36 * PLANE;          // 41,287,680
    constexpr size_t P20 = (size_t)16 * 20 * PLANE;           // 22,937,600

    char* ws = (char*)d_ws;
    size_t off = 0;
    auto carve = [&](size_t bytes) { char* p = ws + off; off += (bytes + 255) & ~(size_t)255; return p; };
    u16* wi0h = (u16*)carve(WI0); u16* wi0l = (u16*)carve(WI0);
    u16* wi1h = (u16*)carve(WI123); u16* wi1l = (u16*)carve(WI123);
    u16* wi2h = (u16*)carve(WI123); u16* wi2l = (u16*)carve(WI123);
    u16* wi3h = (u16*)carve(WI123); u16* wi3l = (u16*)carve(WI123);
    u16* wm0h = (u16*)carve(WM0);
    u16* wm1h = (u16*)carve(WM123); u16* wm2h = (u16*)carve(WM123); u16* wm3h = (u16*)carve(WM123);
    u16* wpjh = (u16*)carve(WPJ);
    u16* X0hi = (u16*)carve(X0SZ);
    char* RGA = carve(X0SZ);        // X0lo -> MBhi
    char* RGB = carve(2 * P20);     // RAhi+RAlo -> MAhi
    char* RGC = carve(2 * P20);     // RBhi+RBlo -> mf
    float* iamb = (float*)carve(1024000);
    int* pos = (int*)carve(256);
    float* denom = (float*)carve(256);
    float* instb = (float*)carve(34560);
    float* pkbuf = (float*)carve(32768);

    u16* X0lo = (u16*)RGA;
    u16* MBhi = (u16*)RGA;
    u16* RAhi = (u16*)RGB; u16* RAlo = (u16*)(RGB + P20);
    u16* MAhi = (u16*)RGB;
    u16* RBhi = (u16*)RGC; u16* RBlo = (u16*)(RGC + P20);
    float* mf = (float*)RGC;

    float* out_logits = (float*)d_out;          // 64*2
    float* out_mask = out_logits + 128;         // 64*67
    float* out_reg = out_mask + 64 * 67;        // 64*67
    float* out_masks = out_reg + 64 * 67;       // 64*4000

    const dim3 blk(256);
    auto rp = [&](const float* W, u16* h, u16* l, int Cout_, int Cin_, int NRS_,
                  int nCh_, int Npad_, int dolo) {
        const int tot = NRS_ * nCh_ * Npad_ * 4;
        repack_w<<<dim3((tot + 255) / 256), blk, 0, stream>>>(W, h, l, Cout_, Cin_, NRS_, nCh_, Npad_, dolo);
    };
    rp(iw0, wi0h, wi0l, 134, 258, 9, 9, 160, 1);
    rp(iw1, wi1h, wi1l, 134, 134, 9, 5, 160, 1);
    rp(iw2, wi2h, wi2l, 134, 134, 9, 5, 160, 1);
    rp(iw3, wi3h, wi3l, 134, 134, 9, 5, 160, 1);
    rp(mw0, wm0h, nullptr, 256, 258, 9, 9, 256, 0);
    rp(mw1, wm1h, nullptr, 256, 256, 9, 8, 256, 0);
    rp(mw2, wm2h, nullptr, 256, 256, 9, 8, 256, 0);
    rp(mw3, wm3h, nullptr, 256, 256, 9, 8, 256, 0);
    rp(pw, wpjh, nullptr, 128, 256, 1, 8, 128, 0);

    const dim3 gH((NPIXH + 255) / 256);
    prep_x0<<<gH, blk, 0, stream>>>(features, X0hi, X0lo);
    zero_halo_pl<<<gH, blk, 0, stream>>>(RAhi, RAlo, 20, 20);

    // ---- inst branch: SPLIT=3 pass-split, single-buffer (r9), BN=64, nN=3 ----
    // nwg = 3*32*16 = 1536, cpx = 192
    conv_mfma<3, 64, 9, 0, 9, 4, 0><<<dim3(1536), blk, 0, stream>>>(
        X0hi, X0lo, wi0h, wi0l, ib0, RAhi, RAlo, nullptr, 160, 134, 160, 20, 1, 3, 192);
    zero_halo_pl<<<gH, blk, 0, stream>>>(RBhi, RBlo, 20, 20);
    conv_mfma<3, 64, 9, 0, 5, 4, 0><<<dim3(1536), blk, 0, stream>>>(
        RAhi, RAlo, wi1h, wi1l, ib1, RBhi, RBlo, nullptr, 160, 134, 160, 20, 1, 3, 192);
    conv_mfma<3, 64, 9, 0, 5, 4, 0><<<dim3(1536), blk, 0, stream>>>(
        RBhi, RBlo, wi2h, wi2l, ib2, RAhi, RAlo, nullptr, 160, 134, 160, 20, 1, 3, 192);
    conv_mfma<3, 64, 9, 0, 5, 4, 0><<<dim3(1536), blk, 0, stream>>>(
        RAhi, RAlo, wi3h, wi3l, ib3, RBhi, RBlo, nullptr, 160, 134, 160, 20, 1, 3, 192);

    iam_conv_nhwc<<<dim3(250), blk, 0, stream>>>(RBhi, RBlo, iam_w, iam_b, iamb);
    stats_kernel<<<dim3(64), blk, 0, stream>>>(iamb, pos, denom);
    inst_nhwc<<<dim3(16, 17), blk, 0, stream>>>(RBhi, RBlo, iamb, denom, instb);
    head_kernel<<<dim3(64), dim3(128), 0, stream>>>(instb, cls_w, cls_b, mk_w, mk_b, out_logits, pkbuf);
    gather_nhwc<<<dim3(64), dim3(192), 0, stream>>>(RBhi, RBlo, pos, out_mask, out_reg);

    // ---- mask branch: SPLIT=1 double-buffer (r12), BN=128, nN=2, MINW=3 ----
    // nwg = 2*32*16 = 1024, cpx = 128
    zero_halo_pl<<<gH, blk, 0, stream>>>(MAhi, MBhi, 32, 32);
    conv_mfma<1, 128, 9, 1, 9, 3, 1><<<dim3(1024), blk, 0, stream>>>(
        X0hi, nullptr, wm0h, nullptr, mb0, MAhi, nullptr, nullptr, 256, 256, 256, 32, 1, 2, 128);
    conv_mfma<1, 128, 9, 1, 8, 3, 1><<<dim3(1024), blk, 0, stream>>>(
        MAhi, nullptr, wm1h, nullptr, mb1, MBhi, nullptr, nullptr, 256, 256, 256, 32, 1, 2, 128);
    conv_mfma<1, 128, 9, 1, 8, 3, 1><<<dim3(1024), blk, 0, stream>>>(
        MBhi, nullptr, wm2h, nullptr, mb2, MAhi, nullptr, nullptr, 256, 256, 256, 32, 1, 2, 128);
    conv_mfma<1, 128, 9, 1, 8, 3, 1><<<dim3(1024), blk, 0, stream>>>(
        MAhi, nullptr, wm3h, nullptr, mb3, MBhi, nullptr, nullptr, 256, 256, 256, 32, 1, 2, 128);
    // proj 1x1: BN=128, nN=1 -> nwg=512, cpx=64
    conv_mfma<1, 128, 1, 2, 8, 3, 1><<<dim3(512), blk, 0, stream>>>(
        MBhi, nullptr, wpjh, nullptr, pb, nullptr, nullptr, mf, 128, 128, 128, 0, 0, 1, 64);

    maskout_nhwc<<<dim3(16, 16), blk, 0, stream>>>(pkbuf, mf, out_masks);
}